// Round 10
// baseline (126.065 us; speedup 1.0000x reference)
//
#include <hip/hip_runtime.h>
#include <math.h>

#define RAD 5
#define SIDE 80
#define SLAB 6400      // 80*80
#define VOL 512000     // 80^3
#define NCH 8          // N*K
#define NCLS 4
#define Q 20           // float4 columns per 80-float row
#define TH 16          // output tile extent along h
#define TW 16          // output tile extent along w
#define NTH 5
#define NTW 5
#define TPC (NTH*NTW)          // 25 tiles per channel
#define NBLK1 (NCH*TPC)        // 200 blocks for the fused kernel
#define SUMB 64                // K0 blocks per channel
#define ROWS 24                // LDS row stride in f4 (2 pad + 20 + 2 pad)
#define VS 21                  // LDS V stride in f4

// exp(-t^2/32) for t=-5..5 (unnormalized Gaussian, symmetric)
__constant__ float GW[11] = {
    0.45783336177161427f, 0.6065306597126334f, 0.7548396019890073f,
    0.8824969025845955f,  0.969233234476344f,  1.0f,
    0.969233234476344f,   0.8824969025845955f, 0.7548396019890073f,
    0.6065306597126334f,  0.45783336177161427f};

// Module-scope scratch. Slot-based cross-kernel dataflow only (no fences/hot atomics).
__device__ float2 g_s1[NCH * SUMB];   // {S_ip, S_p} per K0 block
__device__ float2 g_part[NBLK1];      // {num, den} per K1 block

// K0: per-channel sums S_ip = sum(lab*img), S_p = sum(lab)
__global__ void __launch_bounds__(256) sums_kernel(
        const float* __restrict__ labels, const float* __restrict__ img) {
    const int c = blockIdx.y;
    const int n = c >> 2;
    const float4* lab4 = (const float4*)labels + (size_t)c * (VOL / 4);
    const float4* img4 = (const float4*)img + (size_t)n * (VOL / 4);
    float sip = 0.f, sp = 0.f;
    for (int i = blockIdx.x * 256 + threadIdx.x; i < VOL / 4; i += SUMB * 256) {
        float4 l = lab4[i];
        float4 v = img4[i];
        sip += l.x * v.x + l.y * v.y + l.z * v.z + l.w * v.w;
        sp  += l.x + l.y + l.z + l.w;
    }
    #pragma unroll
    for (int off = 32; off > 0; off >>= 1) {
        sip += __shfl_down(sip, off);
        sp  += __shfl_down(sp, off);
    }
    __shared__ float sm[8];
    const int lane = threadIdx.x & 63;
    const int wid  = threadIdx.x >> 6;
    if (lane == 0) { sm[wid * 2] = sip; sm[wid * 2 + 1] = sp; }
    __syncthreads();
    if (threadIdx.x == 0)
        g_s1[c * SUMB + blockIdx.x] = make_float2(sm[0] + sm[2] + sm[4] + sm[6],
                                                  sm[1] + sm[3] + sm[5] + sm[7]);
}

// K1: fully fused separable conv + weight + dot. One block per 16x16x80 output
// tile; streams 26 h-rows with d-conv (register window) + w-conv (LDS) + h-conv
// (register ring), finalizing straight into the num/den dot. No intermediate
// global buffer.
__global__ void __launch_bounds__(320) conv_dot_kernel(
        const float* __restrict__ labels, const float* __restrict__ img) {
    const int blk = blockIdx.x;
    const int c   = blk / TPC;
    const int r   = blk % TPC;
    const int h0  = (r / NTW) * TH;
    const int w0  = (r % NTW) * TW;
    const int n   = c >> 2;
    const int tid = threadIdx.x;
    const int w_l = tid / Q;      // 0..15
    const int q   = tid % Q;      // 0..19

    __shared__ float4 rowb[2][26 * ROWS];  // staged labels rows (double-buffered)
    __shared__ float4 Vb[2][26 * VS];      // d-conv output (double-buffered)
    __shared__ float sm[10];
    __shared__ float s_mean;

    // per-channel mean from K0 slots (64 float2, L2-resident)
    if (tid < 64) {
        float2 p = g_s1[c * SUMB + tid];
        float a = p.x, b = p.y;
        #pragma unroll
        for (int off = 32; off > 0; off >>= 1) {
            a += __shfl_down(a, off);
            b += __shfl_down(b, off);
        }
        if (tid == 0) s_mean = a / (b + 5.12f);   // VOL*EPS_MEAN
    }
    // zero the d-pad columns of both row buffers (f4 idx 0,1,22,23 per row)
    for (int i = tid; i < 2 * 26 * 4; i += 320) {
        int b = i / 104, rr = (i % 104) >> 2, j = i & 3;
        rowb[b][rr * ROWS + ((j < 2) ? j : (20 + j))] = make_float4(0.f, 0.f, 0.f, 0.f);
    }
    __syncthreads();
    const float mean = s_mean;

    const float4* labc4 = (const float4*)labels + (size_t)c * (VOL / 4);
    const float4* imgc4 = (const float4*)img + (size_t)n * (VOL / 4);

    float4 P[11];
    #pragma unroll
    for (int k = 0; k < 11; ++k) P[k] = make_float4(0.f, 0.f, 0.f, 0.f);
    float num = 0.f, den = 0.f;

    #pragma unroll 2
    for (int it = 0; it < 26; ++it) {
        const int p = it & 1;
        const int h = h0 - RAD + it;
        // stage labels row h (26 w-values x 20 f4), OOB -> 0
        const bool hv = (unsigned)h < SIDE;
        for (int s = tid; s < 26 * Q; s += 320) {
            int ws = s / Q, qs = s - (s / Q) * Q;
            int w = w0 - RAD + ws;
            float4 v = make_float4(0.f, 0.f, 0.f, 0.f);
            if (hv && (unsigned)w < SIDE)
                v = labc4[((size_t)h * SIDE + w) * Q + qs];
            rowb[p][ws * ROWS + 2 + qs] = v;
        }
        __syncthreads();
        // d-conv: register window, 5 b128 reads -> 4 outputs, into Vb
        for (int s = tid; s < 26 * Q; s += 320) {
            int ws = s / Q, qs = s - (s / Q) * Q;
            float a[20];
            #pragma unroll
            for (int j = 0; j < 5; ++j) {
                float4 v = rowb[p][ws * ROWS + qs + j];
                a[4 * j] = v.x; a[4 * j + 1] = v.y;
                a[4 * j + 2] = v.z; a[4 * j + 3] = v.w;
            }
            float s0 = 0.f, s1 = 0.f, s2 = 0.f, s3 = 0.f;
            #pragma unroll
            for (int t = 0; t < 11; ++t) {
                float g = GW[t];
                s0 += g * a[t + 3]; s1 += g * a[t + 4];
                s2 += g * a[t + 5]; s3 += g * a[t + 6];
            }
            Vb[p][ws * VS + qs] = make_float4(s0, s1, s2, s3);
        }
        __syncthreads();
        // w-conv for this thread's (w_out, q): U = conv_w(V)
        float4 U = make_float4(0.f, 0.f, 0.f, 0.f);
        #pragma unroll
        for (int t = 0; t < 11; ++t) {
            float g = GW[t];
            float4 v = Vb[p][(w_l + t) * VS + q];
            U.x += g * v.x; U.y += g * v.y; U.z += g * v.z; U.w += g * v.w;
        }
        // h-conv ring: P[k] holds partial out[h-5+k]
        #pragma unroll
        for (int k = 0; k < 11; ++k) {
            float g = GW[k];
            P[k].x += g * U.x; P[k].y += g * U.y;
            P[k].z += g * U.z; P[k].w += g * U.w;
        }
        // finalize out[m], m = h-5 = h0+it-10, when inside the tile
        if (it >= 10) {
            const int m = h0 + it - 10;
            size_t gi = ((size_t)m * SIDE + (w0 + w_l)) * Q + q;
            float4 l = labc4[gi];
            float4 v = imgc4[gi];
            float4 o = P[0];
            float d0 = v.x - mean, d1 = v.y - mean, d2 = v.z - mean, d3 = v.w - mean;
            float q0 = d0 * d0, q1 = d1 * d1, q2 = d2 * d2, q3 = d3 * d3;
            float e0 = __expf(-q0 * q0), e1 = __expf(-q1 * q1);
            float e2 = __expf(-q2 * q2), e3 = __expf(-q3 * q3);
            num += o.x * l.x * e0 + o.y * l.y * e1 + o.z * l.z * e2 + o.w * l.w * e3;
            den += o.x * e0 + o.y * e1 + o.z * e2 + o.w * e3;
        }
        // shift the ring
        #pragma unroll
        for (int k = 0; k < 10; ++k) P[k] = P[k + 1];
        P[10] = make_float4(0.f, 0.f, 0.f, 0.f);
    }
    // block-reduce num/den over 5 waves -> per-block slot
    #pragma unroll
    for (int off = 32; off > 0; off >>= 1) {
        num += __shfl_down(num, off);
        den += __shfl_down(den, off);
    }
    const int lane = tid & 63;
    const int wid  = tid >> 6;
    if (lane == 0) { sm[wid * 2] = num; sm[wid * 2 + 1] = den; }
    __syncthreads();
    if (tid == 0)
        g_part[blk] = make_float2(sm[0] + sm[2] + sm[4] + sm[6] + sm[8],
                                  sm[1] + sm[3] + sm[5] + sm[7] + sm[9]);
}

// K2: reduce per-block partials -> per-channel ratio -> loss scalar
__global__ void __launch_bounds__(64) final_kernel(float* __restrict__ out) {
    const int t = threadIdx.x;
    float cn[NCH], cd[NCH];
    #pragma unroll
    for (int c = 0; c < NCH; ++c) {
        float a = 0.f, b = 0.f;
        if (t < TPC) { float2 p = g_part[c * TPC + t]; a = p.x; b = p.y; }
        #pragma unroll
        for (int off = 32; off > 0; off >>= 1) {
            a += __shfl_down(a, off);
            b += __shfl_down(b, off);
        }
        cn[c] = a; cd[c] = b;   // valid on lane 0
    }
    if (t == 0) {
        float loss = 0.f;
        #pragma unroll
        for (int k = 0; k < NCLS; ++k) {
            float r0 = cn[k]        / (cd[k]        + 1e-6f);
            float r1 = cn[NCLS + k] / (cd[NCLS + k] + 1e-6f);
            loss += 0.5f * (fabsf(r0) + fabsf(r1));   // mean over N=2, sum over K
        }
        out[0] = (float)NCLS - loss;
    }
}

extern "C" void kernel_launch(void* const* d_in, const int* in_sizes, int n_in,
                              void* d_out, int out_size, void* d_ws, size_t ws_size,
                              hipStream_t stream) {
    const float* labels = (const float*)d_in[0];   // (2,4,80,80,80) f32
    const float* img    = (const float*)d_in[1];   // (2,1,80,80,80) f32
    float* out = (float*)d_out;                    // 1 float
    (void)d_ws; (void)ws_size;                     // module-scope scratch

    hipLaunchKernelGGL(sums_kernel,     dim3(SUMB, NCH), dim3(256), 0, stream, labels, img);
    hipLaunchKernelGGL(conv_dot_kernel, dim3(NBLK1),     dim3(320), 0, stream, labels, img);
    hipLaunchKernelGGL(final_kernel,    dim3(1),         dim3(64),  0, stream, out);
}

// Round 11
// 102.544 us; speedup vs baseline: 1.2294x; 1.2294x over previous
//
#include <hip/hip_runtime.h>
#include <math.h>

#define RAD 5
#define SIDE 80
#define SLAB 6400      // 80*80
#define VOL 512000     // 80^3
#define NCH 8          // N*K
#define NCLS 4
#define Q 20           // float4 columns per 80-float row
#define TBS 22         // tB row stride in float4

// K1 tiling: w-tile 40, halo 5 each side -> 50 staged rows, 1.25x redundancy
#define WT 40
#define K1ROWS 50          // WT + 2*RAD
#define NWT 2              // w-tiles per axis
#define C1 (SIDE*NWT)      // 160 K1 slots per channel
#define NBLK1 (NCH*C1)     // 1280 K1 blocks

// K2 tiling: 8 h-outputs per thread, 320-thread blocks, 50 blocks per channel
#define K2T 320
#define K2PB 50
#define NBLK2 (NCH*K2PB)   // 400 K2 blocks

// exp(-t^2/32) for t=-5..5 (unnormalized Gaussian, symmetric)
__constant__ float GW[11] = {
    0.45783336177161427f, 0.6065306597126334f, 0.7548396019890073f,
    0.8824969025845955f,  0.969233234476344f,  1.0f,
    0.969233234476344f,   0.8824969025845955f, 0.7548396019890073f,
    0.6065306597126334f,  0.45783336177161427f};

// Module-scope scratch. Slot-based cross-kernel dataflow ONLY:
// R8 measured device atomics+fences at ~+100 µs/kernel; R7 measured
// grid.sync at ~+550 µs. Kernel boundaries are the sync primitive.
__device__ float  g_bufT[(size_t)NCH * VOL];  // d+w-conv'd labels, [c][w][h][d]
__device__ float2 g_part1[NBLK1];             // {S_ip, S_p} per K1 block
__device__ float2 g_part2[NBLK2];             // {num, den} per K2 block

// K1: per (c, h, w-tile40): d-conv via register window from global,
// fused channel sums, w-conv via LDS gather, transposed store to g_bufT.
__global__ void __launch_bounds__(256) convdw_sums_kernel(
        const float* __restrict__ labels, const float* __restrict__ img) {
    const int tile = blockIdx.x;
    const int c   = tile / C1;
    const int rem = tile % C1;
    const int h   = rem / NWT;
    const int w0  = (rem % NWT) * WT;
    const int n   = c >> 2;

    __shared__ float4 tB[K1ROWS * TBS];   // d-conv result rows w0-5..w0+44
    __shared__ float sm[8];

    const float4* labc4 = (const float4*)labels + ((size_t)c * SIDE + h) * Q * SIDE / 4 * 4 / (Q * 4) * 0;  // (unused guard)
    labc4 = (const float4*)(labels + ((size_t)c * SIDE + h) * SLAB);
    const float4* imgc4 = (const float4*)(img + ((size_t)n * SIDE + h) * SLAB);

    float sip = 0.f, sp = 0.f;
    for (int i = threadIdx.x; i < K1ROWS * Q; i += 256) {
        const int r = i / Q, q = i - (i / Q) * Q;
        const int w = w0 - RAD + r;
        float a[20];
        #pragma unroll
        for (int j = 0; j < 20; ++j) a[j] = 0.f;
        if ((unsigned)w < SIDE) {
            const float4* row = labc4 + (size_t)w * Q;
            #pragma unroll
            for (int j = 0; j < 5; ++j) {
                int qq = q - 2 + j;
                if (qq >= 0 && qq < Q) {
                    float4 v = row[qq];
                    a[4 * j] = v.x; a[4 * j + 1] = v.y;
                    a[4 * j + 2] = v.z; a[4 * j + 3] = v.w;
                }
            }
            if (r >= RAD && r < RAD + WT) {   // central rows: fused channel sums
                float4 v = imgc4[(size_t)w * Q + q];
                sip += a[8] * v.x + a[9] * v.y + a[10] * v.z + a[11] * v.w;
                sp  += a[8] + a[9] + a[10] + a[11];
            }
        }
        float s0 = 0.f, s1 = 0.f, s2 = 0.f, s3 = 0.f;
        #pragma unroll
        for (int t = 0; t < 11; ++t) {
            float g = GW[t];
            s0 += g * a[t + 3]; s1 += g * a[t + 4];
            s2 += g * a[t + 5]; s3 += g * a[t + 6];
        }
        tB[r * TBS + q] = make_float4(s0, s1, s2, s3);
    }
    // block-reduce sums (same barrier covers tB completion + sm visibility)
    #pragma unroll
    for (int off = 32; off > 0; off >>= 1) {
        sip += __shfl_down(sip, off);
        sp  += __shfl_down(sp, off);
    }
    const int lane = threadIdx.x & 63;
    const int wid  = threadIdx.x >> 6;
    if (lane == 0) { sm[wid * 2] = sip; sm[wid * 2 + 1] = sp; }
    __syncthreads();
    if (threadIdx.x == 0)
        g_part1[tile] = make_float2(sm[0] + sm[2] + sm[4] + sm[6],
                                    sm[1] + sm[3] + sm[5] + sm[7]);
    // w-conv (11-tap LDS gather) + transposed float4 store
    float* outc = g_bufT + (size_t)c * VOL + (size_t)h * SIDE;
    for (int i = threadIdx.x; i < WT * Q; i += 256) {
        const int rl = i / Q, q = i - (i / Q) * Q;
        float sx = 0.f, sy = 0.f, sz = 0.f, sw = 0.f;
        #pragma unroll
        for (int t = 0; t < 11; ++t) {
            float g = GW[t];
            float4 v = tB[(rl + t) * TBS + q];
            sx += g * v.x; sy += g * v.y; sz += g * v.z; sw += g * v.w;
        }
        ((float4*)(outc + (size_t)(w0 + rl) * SLAB))[q] = make_float4(sx, sy, sz, sw);
    }
}

// K2: register sliding-window conv along H straight from g_bufT (no LDS conv),
// fused weight + dot. Thread = (c, hq, w, q) producing 8 h-outputs.
__global__ void __launch_bounds__(K2T) convh_dot_kernel(
        const float* __restrict__ labels, const float* __restrict__ img) {
    const int c   = blockIdx.x / K2PB;
    const int rem = (blockIdx.x % K2PB) * K2T + threadIdx.x;   // 0..15999
    const int hq  = rem / 1600;          // 10 h-groups of 8
    const int r2  = rem % 1600;
    const int w   = r2 / Q;
    const int q   = r2 % Q;
    const int h0  = hq * 8;
    const int n   = c >> 2;

    __shared__ float sm[10];
    __shared__ float s_mean;

    // per-channel mean from K1 partials (block-redundant; L2-resident, 1.3 KB)
    float a = 0.f, b = 0.f;
    for (int t = threadIdx.x; t < C1; t += K2T) {
        float2 p = g_part1[c * C1 + t];
        a += p.x; b += p.y;
    }
    #pragma unroll
    for (int off = 32; off > 0; off >>= 1) {
        a += __shfl_down(a, off);
        b += __shfl_down(b, off);
    }
    const int lane = threadIdx.x & 63;
    const int wid  = threadIdx.x >> 6;
    if (lane == 0) { sm[wid * 2] = a; sm[wid * 2 + 1] = b; }
    __syncthreads();
    if (threadIdx.x == 0)
        s_mean = (sm[0] + sm[2] + sm[4] + sm[6] + sm[8]) /
                 (sm[1] + sm[3] + sm[5] + sm[7] + sm[9] + 5.12f);  // VOL*EPS_MEAN
    __syncthreads();
    const float mean = s_mean;

    // sliding window: g_bufT[c][w][h0-5 .. h0+12][q]  (18 f4, OOB -> 0)
    const float4* bc4 = (const float4*)g_bufT + (size_t)c * (VOL / 4) + (size_t)w * (SLAB / 4);
    float4 win[18];
    #pragma unroll
    for (int m = 0; m < 18; ++m) {
        int hh = h0 - RAD + m;
        win[m] = ((unsigned)hh < SIDE) ? bc4[hh * Q + q]
                                       : make_float4(0.f, 0.f, 0.f, 0.f);
    }
    const float4* labp4 = (const float4*)labels + (size_t)c * (VOL / 4);
    const float4* imgp4 = (const float4*)img + (size_t)n * (VOL / 4);
    float num = 0.f, den = 0.f;
    #pragma unroll
    for (int k = 0; k < 8; ++k) {
        float sx = 0.f, sy = 0.f, sz = 0.f, sw = 0.f;
        #pragma unroll
        for (int t = 0; t < 11; ++t) {
            float g = GW[t];
            float4 v = win[k + t];
            sx += g * v.x; sy += g * v.y; sz += g * v.z; sw += g * v.w;
        }
        size_t gi = (size_t)(h0 + k) * (SLAB / 4) + (size_t)w * Q + q;
        float4 l = labp4[gi];
        float4 v = imgp4[gi];
        float d0 = v.x - mean, d1 = v.y - mean, d2 = v.z - mean, d3 = v.w - mean;
        float q0 = d0 * d0, q1 = d1 * d1, q2 = d2 * d2, q3 = d3 * d3;
        float e0 = __expf(-q0 * q0), e1 = __expf(-q1 * q1);
        float e2 = __expf(-q2 * q2), e3 = __expf(-q3 * q3);
        num += sx * l.x * e0 + sy * l.y * e1 + sz * l.z * e2 + sw * l.w * e3;
        den += sx * e0 + sy * e1 + sz * e2 + sw * e3;
    }
    #pragma unroll
    for (int off = 32; off > 0; off >>= 1) {
        num += __shfl_down(num, off);
        den += __shfl_down(den, off);
    }
    if (lane == 0) { sm[wid * 2] = num; sm[wid * 2 + 1] = den; }
    __syncthreads();
    if (threadIdx.x == 0)
        g_part2[blockIdx.x] = make_float2(sm[0] + sm[2] + sm[4] + sm[6] + sm[8],
                                          sm[1] + sm[3] + sm[5] + sm[7] + sm[9]);
}

// K3: reduce K2's per-block partials -> per-channel ratio -> loss scalar
__global__ void __launch_bounds__(64) final_kernel(float* __restrict__ out) {
    const int t = threadIdx.x;
    float cn[NCH], cd[NCH];
    #pragma unroll
    for (int c = 0; c < NCH; ++c) {
        float a = 0.f, b = 0.f;
        if (t < K2PB) { float2 p = g_part2[c * K2PB + t]; a = p.x; b = p.y; }
        #pragma unroll
        for (int off = 32; off > 0; off >>= 1) {
            a += __shfl_down(a, off);
            b += __shfl_down(b, off);
        }
        cn[c] = a; cd[c] = b;   // valid on lane 0
    }
    if (t == 0) {
        float loss = 0.f;
        #pragma unroll
        for (int k = 0; k < NCLS; ++k) {
            float r0 = cn[k]        / (cd[k]        + 1e-6f);
            float r1 = cn[NCLS + k] / (cd[NCLS + k] + 1e-6f);
            loss += 0.5f * (fabsf(r0) + fabsf(r1));   // mean over N=2, sum over K
        }
        out[0] = (float)NCLS - loss;
    }
}

extern "C" void kernel_launch(void* const* d_in, const int* in_sizes, int n_in,
                              void* d_out, int out_size, void* d_ws, size_t ws_size,
                              hipStream_t stream) {
    const float* labels = (const float*)d_in[0];   // (2,4,80,80,80) f32
    const float* img    = (const float*)d_in[1];   // (2,1,80,80,80) f32
    float* out = (float*)d_out;                    // 1 float
    (void)d_ws; (void)ws_size;                     // module-scope scratch

    hipLaunchKernelGGL(convdw_sums_kernel, dim3(NBLK1), dim3(256), 0, stream, labels, img);
    hipLaunchKernelGGL(convh_dot_kernel,   dim3(NBLK2), dim3(K2T), 0, stream, labels, img);
    hipLaunchKernelGGL(final_kernel,       dim3(1),     dim3(64),  0, stream, out);
}

// Round 12
// 99.395 us; speedup vs baseline: 1.2683x; 1.0317x over previous
//
#include <hip/hip_runtime.h>
#include <math.h>

#define RAD 5
#define SIDE 80
#define SLAB 6400      // 80*80
#define VOL 512000     // 80^3
#define NCH 8          // N*K
#define NCLS 4
#define Q 20           // float4/ushort4 columns per 80-elem row
#define TW 16          // K1 tile extent along w
#define NT 5           // w-tiles per axis (80/16)
#define C1 (SIDE*NT)           // 400 K1 slots per channel
#define NBLK1 (NCH*C1)         // 3200 K1 blocks
#define TBS 22                 // tB row stride in float4
#define K2PB 250               // K2 blocks per channel
#define NBLK2 (NCH*K2PB)       // 2000 K2 blocks (2 h-outputs per thread)

// exp(-t^2/32) for t=-5..5 (unnormalized Gaussian, symmetric)
__constant__ float GW[11] = {
    0.45783336177161427f, 0.6065306597126334f, 0.7548396019890073f,
    0.8824969025845955f,  0.969233234476344f,  1.0f,
    0.969233234476344f,   0.8824969025845955f, 0.7548396019890073f,
    0.6065306597126334f,  0.45783336177161427f};

// Module-scope scratch. Slot-based cross-kernel dataflow ONLY:
// R8: device atomics+fences = +100 µs/kernel; R7: grid.sync = +550 µs.
// Kernel boundaries are the only sync primitive used.
__device__ unsigned short g_bufT[(size_t)NCH * VOL];  // bf16 d+w-conv'd labels, [c][w][h][d]
__device__ float2 g_part1[NBLK1];             // {S_ip, S_p} per K1 block
__device__ float2 g_part2[NBLK2];             // {num, den} per K2 block

__device__ __forceinline__ unsigned short f2bf(float f) {
    unsigned u = __float_as_uint(f);
    u += 0x7FFFu + ((u >> 16) & 1u);          // round-to-nearest-even
    return (unsigned short)(u >> 16);
}
__device__ __forceinline__ float bf2f(unsigned short h) {
    return __uint_as_float((unsigned)h << 16);
}

// K1: per (c, h, w-tile16): d-conv via register window from global,
// fused channel sums, w-conv via LDS gather, transposed bf16 store to g_bufT.
__global__ void __launch_bounds__(256) convdw_sums_kernel(
        const float* __restrict__ labels, const float* __restrict__ img) {
    const int tile = blockIdx.x;
    const int c   = tile / C1;
    const int rem = tile % C1;
    const int h   = rem / NT;
    const int w0  = (rem % NT) * TW;
    const int n   = c >> 2;

    __shared__ float4 tB[26 * TBS];   // d-conv result rows w0-5..w0+20
    __shared__ float sm[8];

    const float4* labc4 = (const float4*)(labels + ((size_t)c * SIDE + h) * SLAB);
    const float4* imgc4 = (const float4*)(img + ((size_t)n * SIDE + h) * SLAB);

    float sip = 0.f, sp = 0.f;
    for (int i = threadIdx.x; i < 26 * Q; i += 256) {
        const int r = i / Q, q = i - (i / Q) * Q;
        const int w = w0 - RAD + r;
        float a[20];
        #pragma unroll
        for (int j = 0; j < 20; ++j) a[j] = 0.f;
        if ((unsigned)w < SIDE) {
            const float4* row = labc4 + (size_t)w * Q;
            #pragma unroll
            for (int j = 0; j < 5; ++j) {
                int qq = q - 2 + j;
                if (qq >= 0 && qq < Q) {
                    float4 v = row[qq];
                    a[4 * j] = v.x; a[4 * j + 1] = v.y;
                    a[4 * j + 2] = v.z; a[4 * j + 3] = v.w;
                }
            }
            if (r >= RAD && r < RAD + TW) {   // central rows: fused channel sums
                float4 v = imgc4[(size_t)w * Q + q];
                sip += a[8] * v.x + a[9] * v.y + a[10] * v.z + a[11] * v.w;
                sp  += a[8] + a[9] + a[10] + a[11];
            }
        }
        float s0 = 0.f, s1 = 0.f, s2 = 0.f, s3 = 0.f;
        #pragma unroll
        for (int t = 0; t < 11; ++t) {
            float g = GW[t];
            s0 += g * a[t + 3]; s1 += g * a[t + 4];
            s2 += g * a[t + 5]; s3 += g * a[t + 6];
        }
        tB[r * TBS + q] = make_float4(s0, s1, s2, s3);
    }
    // block-reduce sums (same barrier covers tB completion + sm visibility)
    #pragma unroll
    for (int off = 32; off > 0; off >>= 1) {
        sip += __shfl_down(sip, off);
        sp  += __shfl_down(sp, off);
    }
    const int lane = threadIdx.x & 63;
    const int wid  = threadIdx.x >> 6;
    if (lane == 0) { sm[wid * 2] = sip; sm[wid * 2 + 1] = sp; }
    __syncthreads();
    if (threadIdx.x == 0)
        g_part1[tile] = make_float2(sm[0] + sm[2] + sm[4] + sm[6],
                                    sm[1] + sm[3] + sm[5] + sm[7]);
    // w-conv (11-tap LDS gather) + transposed bf16 ushort4 store
    ushort4* out4 = (ushort4*)g_bufT + ((size_t)c * VOL + (size_t)h * SIDE) / 4;
    for (int i = threadIdx.x; i < TW * Q; i += 256) {
        const int rl = i / Q, q = i - (i / Q) * Q;
        float sx = 0.f, sy = 0.f, sz = 0.f, sw = 0.f;
        #pragma unroll
        for (int t = 0; t < 11; ++t) {
            float g = GW[t];
            float4 v = tB[(rl + t) * TBS + q];
            sx += g * v.x; sy += g * v.y; sz += g * v.z; sw += g * v.w;
        }
        ushort4 o;
        o.x = f2bf(sx); o.y = f2bf(sy); o.z = f2bf(sz); o.w = f2bf(sw);
        out4[(size_t)(w0 + rl) * (SLAB / 4) + q] = o;
    }
}

// K2: register sliding-window conv along H from bf16 g_bufT (no LDS conv),
// fused weight + dot. Thread = (c, h-pair, w, q) producing 2 h-outputs.
__global__ void __launch_bounds__(256) convh_dot_kernel(
        const float* __restrict__ labels, const float* __restrict__ img) {
    const int c   = blockIdx.x / K2PB;
    const int rem = (blockIdx.x % K2PB) * 256 + threadIdx.x;   // 0..63999
    const int hp  = rem / 1600;          // 40 h-pairs
    const int r2  = rem % 1600;
    const int w   = r2 / Q;
    const int q   = r2 % Q;
    const int h0  = hp * 2;
    const int n   = c >> 2;

    __shared__ float sm[8];
    __shared__ float s_mean;

    // per-channel mean from K1 partials (block-redundant; L2-resident, 3.2 KB)
    float a = 0.f, b = 0.f;
    for (int t = threadIdx.x; t < C1; t += 256) {
        float2 p = g_part1[c * C1 + t];
        a += p.x; b += p.y;
    }
    #pragma unroll
    for (int off = 32; off > 0; off >>= 1) {
        a += __shfl_down(a, off);
        b += __shfl_down(b, off);
    }
    const int lane = threadIdx.x & 63;
    const int wid  = threadIdx.x >> 6;
    if (lane == 0) { sm[wid * 2] = a; sm[wid * 2 + 1] = b; }
    __syncthreads();
    if (threadIdx.x == 0)
        s_mean = (sm[0] + sm[2] + sm[4] + sm[6]) /
                 (sm[1] + sm[3] + sm[5] + sm[7] + 5.12f);   // VOL*EPS_MEAN
    __syncthreads();
    const float mean = s_mean;

    // sliding window: g_bufT[c][w][h0-5 .. h0+6][q]  (12 ushort4, OOB -> 0)
    const ushort4* bc4 = (const ushort4*)g_bufT + ((size_t)c * VOL + (size_t)w * SLAB) / 4;
    float4 win[12];
    #pragma unroll
    for (int m = 0; m < 12; ++m) {
        int hh = h0 - RAD + m;
        if ((unsigned)hh < SIDE) {
            ushort4 u = bc4[hh * (SIDE / 4) + q];
            win[m] = make_float4(bf2f(u.x), bf2f(u.y), bf2f(u.z), bf2f(u.w));
        } else {
            win[m] = make_float4(0.f, 0.f, 0.f, 0.f);
        }
    }
    const float4* labp4 = (const float4*)labels + (size_t)c * (VOL / 4);
    const float4* imgp4 = (const float4*)img + (size_t)n * (VOL / 4);
    float num = 0.f, den = 0.f;
    #pragma unroll
    for (int k = 0; k < 2; ++k) {
        float sx = 0.f, sy = 0.f, sz = 0.f, sw = 0.f;
        #pragma unroll
        for (int t = 0; t < 11; ++t) {
            float g = GW[t];
            float4 v = win[k + t];
            sx += g * v.x; sy += g * v.y; sz += g * v.z; sw += g * v.w;
        }
        size_t gi = (size_t)(h0 + k) * (SLAB / 4) + (size_t)w * Q + q;
        float4 l = labp4[gi];
        float4 v = imgp4[gi];
        float d0 = v.x - mean, d1 = v.y - mean, d2 = v.z - mean, d3 = v.w - mean;
        float q0 = d0 * d0, q1 = d1 * d1, q2 = d2 * d2, q3 = d3 * d3;
        float e0 = __expf(-q0 * q0), e1 = __expf(-q1 * q1);
        float e2 = __expf(-q2 * q2), e3 = __expf(-q3 * q3);
        num += sx * l.x * e0 + sy * l.y * e1 + sz * l.z * e2 + sw * l.w * e3;
        den += sx * e0 + sy * e1 + sz * e2 + sw * e3;
    }
    #pragma unroll
    for (int off = 32; off > 0; off >>= 1) {
        num += __shfl_down(num, off);
        den += __shfl_down(den, off);
    }
    if (lane == 0) { sm[wid * 2] = num; sm[wid * 2 + 1] = den; }
    __syncthreads();
    if (threadIdx.x == 0)
        g_part2[blockIdx.x] = make_float2(sm[0] + sm[2] + sm[4] + sm[6],
                                          sm[1] + sm[3] + sm[5] + sm[7]);
}

// K3: reduce K2's per-block partials -> per-channel ratio -> loss scalar
__global__ void __launch_bounds__(256) final_kernel(float* __restrict__ out) {
    __shared__ float sm[8];
    __shared__ float cn[NCH], cd[NCH];
    const int lane = threadIdx.x & 63;
    const int wid  = threadIdx.x >> 6;
    for (int c = 0; c < NCH; ++c) {
        float a = 0.f, b = 0.f;
        for (int t = threadIdx.x; t < K2PB; t += 256) {
            float2 p = g_part2[c * K2PB + t];
            a += p.x; b += p.y;
        }
        #pragma unroll
        for (int off = 32; off > 0; off >>= 1) {
            a += __shfl_down(a, off);
            b += __shfl_down(b, off);
        }
        if (lane == 0) { sm[wid * 2] = a; sm[wid * 2 + 1] = b; }
        __syncthreads();
        if (threadIdx.x == 0) {
            cn[c] = sm[0] + sm[2] + sm[4] + sm[6];
            cd[c] = sm[1] + sm[3] + sm[5] + sm[7];
        }
        __syncthreads();
    }
    if (threadIdx.x == 0) {
        float loss = 0.f;
        for (int k = 0; k < NCLS; ++k) {
            float r0 = cn[k]        / (cd[k]        + 1e-6f);
            float r1 = cn[NCLS + k] / (cd[NCLS + k] + 1e-6f);
            loss += 0.5f * (fabsf(r0) + fabsf(r1));   // mean over N=2, sum over K
        }
        out[0] = (float)NCLS - loss;
    }
}

extern "C" void kernel_launch(void* const* d_in, const int* in_sizes, int n_in,
                              void* d_out, int out_size, void* d_ws, size_t ws_size,
                              hipStream_t stream) {
    const float* labels = (const float*)d_in[0];   // (2,4,80,80,80) f32
    const float* img    = (const float*)d_in[1];   // (2,1,80,80,80) f32
    float* out = (float*)d_out;                    // 1 float
    (void)d_ws; (void)ws_size;                     // module-scope scratch

    hipLaunchKernelGGL(convdw_sums_kernel, dim3(NBLK1), dim3(256), 0, stream, labels, img);
    hipLaunchKernelGGL(convh_dot_kernel,   dim3(NBLK2), dim3(256), 0, stream, labels, img);
    hipLaunchKernelGGL(final_kernel,       dim3(1),     dim3(256), 0, stream, out);
}

// Round 13
// 95.507 us; speedup vs baseline: 1.3200x; 1.0407x over previous
//
#include <hip/hip_runtime.h>
#include <math.h>

#define RAD 5
#define SIDE 80
#define SLAB 6400      // 80*80
#define VOL 512000     // 80^3
#define NCH 8          // N*K
#define NCLS 4
#define Q 20           // float4/ushort4 columns per 80-elem row
#define TW 16          // K1 tile extent along w
#define NT 5           // w-tiles per axis (80/16)
#define C1 (SIDE*NT)           // 400 K1 slots per channel
#define NBLK1 (NCH*C1)         // 3200 K1 blocks
#define TBS 22                 // tB row stride in float4
#define NBLK2 1000             // K2 blocks (4 h-outputs/thread, 125 per channel)
#define CPB 125                // K2 blocks per channel

// exp(-t^2/32) for t=-5..5 (unnormalized Gaussian, symmetric)
__constant__ float GW[11] = {
    0.45783336177161427f, 0.6065306597126334f, 0.7548396019890073f,
    0.8824969025845955f,  0.969233234476344f,  1.0f,
    0.969233234476344f,   0.8824969025845955f, 0.7548396019890073f,
    0.6065306597126334f,  0.45783336177161427f};

// Module-scope scratch. Slot-based cross-kernel dataflow ONLY:
// R8: device atomics+fences = +100 µs/kernel; R7: grid.sync = +550 µs.
// Kernel boundaries are the only sync primitive used.
__device__ unsigned short g_bufT[(size_t)NCH * VOL];  // bf16 conv'd labels, [c][w][h][d]
__device__ float2 g_part1[NBLK1];             // {S_ip, S_p} per K1 block
__device__ float2 g_part2[NBLK2];             // {num, den} per K2 block

__device__ __forceinline__ unsigned short f2bf(float f) {
    unsigned u = __float_as_uint(f);
    u += 0x7FFFu + ((u >> 16) & 1u);          // round-to-nearest-even
    return (unsigned short)(u >> 16);
}
__device__ __forceinline__ float bf2f(unsigned short h) {
    return __uint_as_float((unsigned)h << 16);
}

// K1: per (c, h, w-tile16): d-conv via register window from global,
// fused channel sums, w-conv via LDS gather, transposed bf16 store to g_bufT.
// (R9's exact shape — fastest measured — with bf16 store as the only delta.)
__global__ void __launch_bounds__(256) convdw_sums_kernel(
        const float* __restrict__ labels, const float* __restrict__ img) {
    const int tile = blockIdx.x;
    const int c   = tile / C1;
    const int rem = tile % C1;
    const int h   = rem / NT;
    const int w0  = (rem % NT) * TW;
    const int n   = c >> 2;

    __shared__ float4 tB[26 * TBS];   // d-conv result rows w0-5..w0+20
    __shared__ float sm[8];

    const float4* labc4 = (const float4*)(labels + ((size_t)c * SIDE + h) * SLAB);
    const float4* imgc4 = (const float4*)(img + ((size_t)n * SIDE + h) * SLAB);

    float sip = 0.f, sp = 0.f;
    for (int i = threadIdx.x; i < 26 * Q; i += 256) {
        const int r = i / Q, q = i - (i / Q) * Q;
        const int w = w0 - RAD + r;
        float a[20];
        #pragma unroll
        for (int j = 0; j < 20; ++j) a[j] = 0.f;
        if ((unsigned)w < SIDE) {
            const float4* row = labc4 + (size_t)w * Q;
            #pragma unroll
            for (int j = 0; j < 5; ++j) {
                int qq = q - 2 + j;
                if (qq >= 0 && qq < Q) {
                    float4 v = row[qq];
                    a[4 * j] = v.x; a[4 * j + 1] = v.y;
                    a[4 * j + 2] = v.z; a[4 * j + 3] = v.w;
                }
            }
            if (r >= RAD && r < RAD + TW) {   // central rows: fused channel sums
                float4 v = imgc4[(size_t)w * Q + q];
                sip += a[8] * v.x + a[9] * v.y + a[10] * v.z + a[11] * v.w;
                sp  += a[8] + a[9] + a[10] + a[11];
            }
        }
        float s0 = 0.f, s1 = 0.f, s2 = 0.f, s3 = 0.f;
        #pragma unroll
        for (int t = 0; t < 11; ++t) {
            float g = GW[t];
            s0 += g * a[t + 3]; s1 += g * a[t + 4];
            s2 += g * a[t + 5]; s3 += g * a[t + 6];
        }
        tB[r * TBS + q] = make_float4(s0, s1, s2, s3);
    }
    // block-reduce sums (same barrier covers tB completion + sm visibility)
    #pragma unroll
    for (int off = 32; off > 0; off >>= 1) {
        sip += __shfl_down(sip, off);
        sp  += __shfl_down(sp, off);
    }
    const int lane = threadIdx.x & 63;
    const int wid  = threadIdx.x >> 6;
    if (lane == 0) { sm[wid * 2] = sip; sm[wid * 2 + 1] = sp; }
    __syncthreads();
    if (threadIdx.x == 0)
        g_part1[tile] = make_float2(sm[0] + sm[2] + sm[4] + sm[6],
                                    sm[1] + sm[3] + sm[5] + sm[7]);
    // w-conv (11-tap LDS gather) + transposed bf16 ushort4 store
    ushort4* out4 = (ushort4*)g_bufT + ((size_t)c * VOL + (size_t)h * SIDE) / 4;
    for (int i = threadIdx.x; i < TW * Q; i += 256) {
        const int rl = i / Q, q = i - (i / Q) * Q;
        float sx = 0.f, sy = 0.f, sz = 0.f, sw = 0.f;
        #pragma unroll
        for (int t = 0; t < 11; ++t) {
            float g = GW[t];
            float4 v = tB[(rl + t) * TBS + q];
            sx += g * v.x; sy += g * v.y; sz += g * v.z; sw += g * v.w;
        }
        ushort4 o;
        o.x = f2bf(sx); o.y = f2bf(sy); o.z = f2bf(sz); o.w = f2bf(sw);
        out4[(size_t)(w0 + rl) * (SLAB / 4) + q] = o;
    }
}

// K2: register sliding-window conv along H from bf16 g_bufT (no LDS conv),
// fused weight + dot. Thread = (c, hq, w, q) producing 4 h-outputs.
// (R9's exact shape — 1000 blocks, win[14] — reading bf16.)
__global__ void __launch_bounds__(256) convh_dot_kernel(
        const float* __restrict__ labels, const float* __restrict__ img) {
    const int c   = blockIdx.x / CPB;
    const int rem = (blockIdx.x % CPB) * 256 + threadIdx.x;   // 0..31999
    const int hq  = rem / 1600;          // 20 h-quads
    const int r2  = rem % 1600;
    const int w   = r2 / Q;
    const int q   = r2 % Q;
    const int h0  = hq * 4;
    const int n   = c >> 2;

    __shared__ float sm[8];
    __shared__ float s_mean;

    // per-channel mean from K1 partials (block-redundant; L2-resident, 3.2 KB)
    float a = 0.f, b = 0.f;
    for (int t = threadIdx.x; t < C1; t += 256) {
        float2 p = g_part1[c * C1 + t];
        a += p.x; b += p.y;
    }
    #pragma unroll
    for (int off = 32; off > 0; off >>= 1) {
        a += __shfl_down(a, off);
        b += __shfl_down(b, off);
    }
    const int lane = threadIdx.x & 63;
    const int wid  = threadIdx.x >> 6;
    if (lane == 0) { sm[wid * 2] = a; sm[wid * 2 + 1] = b; }
    __syncthreads();
    if (threadIdx.x == 0)
        s_mean = (sm[0] + sm[2] + sm[4] + sm[6]) /
                 (sm[1] + sm[3] + sm[5] + sm[7] + 5.12f);   // VOL*EPS_MEAN
    __syncthreads();
    const float mean = s_mean;

    // sliding window: g_bufT[c][w][h0-5 .. h0+8][q]  (14 ushort4, OOB -> 0)
    const ushort4* bc4 = (const ushort4*)g_bufT + ((size_t)c * VOL + (size_t)w * SLAB) / 4;
    float4 win[14];
    #pragma unroll
    for (int m = 0; m < 14; ++m) {
        int hh = h0 - RAD + m;
        if ((unsigned)hh < SIDE) {
            ushort4 u = bc4[hh * Q + q];
            win[m] = make_float4(bf2f(u.x), bf2f(u.y), bf2f(u.z), bf2f(u.w));
        } else {
            win[m] = make_float4(0.f, 0.f, 0.f, 0.f);
        }
    }
    const float4* labp4 = (const float4*)labels + (size_t)c * (VOL / 4);
    const float4* imgp4 = (const float4*)img + (size_t)n * (VOL / 4);
    float num = 0.f, den = 0.f;
    #pragma unroll
    for (int k = 0; k < 4; ++k) {
        float sx = 0.f, sy = 0.f, sz = 0.f, sw = 0.f;
        #pragma unroll
        for (int t = 0; t < 11; ++t) {
            float g = GW[t];
            float4 v = win[k + t];
            sx += g * v.x; sy += g * v.y; sz += g * v.z; sw += g * v.w;
        }
        size_t gi = (size_t)(h0 + k) * (SLAB / 4) + (size_t)w * Q + q;
        float4 l = labp4[gi];
        float4 v = imgp4[gi];
        float d0 = v.x - mean, d1 = v.y - mean, d2 = v.z - mean, d3 = v.w - mean;
        float q0 = d0 * d0, q1 = d1 * d1, q2 = d2 * d2, q3 = d3 * d3;
        float e0 = __expf(-q0 * q0), e1 = __expf(-q1 * q1);
        float e2 = __expf(-q2 * q2), e3 = __expf(-q3 * q3);
        num += sx * l.x * e0 + sy * l.y * e1 + sz * l.z * e2 + sw * l.w * e3;
        den += sx * e0 + sy * e1 + sz * e2 + sw * e3;
    }
    #pragma unroll
    for (int off = 32; off > 0; off >>= 1) {
        num += __shfl_down(num, off);
        den += __shfl_down(den, off);
    }
    if (lane == 0) { sm[wid * 2] = num; sm[wid * 2 + 1] = den; }
    __syncthreads();
    if (threadIdx.x == 0)
        g_part2[blockIdx.x] = make_float2(sm[0] + sm[2] + sm[4] + sm[6],
                                          sm[1] + sm[3] + sm[5] + sm[7]);
}

// K3: reduce K2's per-block partials -> per-channel ratio -> loss scalar
__global__ void __launch_bounds__(256) final_kernel(float* __restrict__ out) {
    __shared__ float sm[8];
    __shared__ float cn[NCH], cd[NCH];
    const int lane = threadIdx.x & 63;
    const int wid  = threadIdx.x >> 6;
    for (int c = 0; c < NCH; ++c) {
        float a = 0.f, b = 0.f;
        for (int t = threadIdx.x; t < CPB; t += 256) {
            float2 p = g_part2[c * CPB + t];
            a += p.x; b += p.y;
        }
        #pragma unroll
        for (int off = 32; off > 0; off >>= 1) {
            a += __shfl_down(a, off);
            b += __shfl_down(b, off);
        }
        if (lane == 0) { sm[wid * 2] = a; sm[wid * 2 + 1] = b; }
        __syncthreads();
        if (threadIdx.x == 0) {
            cn[c] = sm[0] + sm[2] + sm[4] + sm[6];
            cd[c] = sm[1] + sm[3] + sm[5] + sm[7];
        }
        __syncthreads();
    }
    if (threadIdx.x == 0) {
        float loss = 0.f;
        for (int k = 0; k < NCLS; ++k) {
            float r0 = cn[k]        / (cd[k]        + 1e-6f);
            float r1 = cn[NCLS + k] / (cd[NCLS + k] + 1e-6f);
            loss += 0.5f * (fabsf(r0) + fabsf(r1));   // mean over N=2, sum over K
        }
        out[0] = (float)NCLS - loss;
    }
}

extern "C" void kernel_launch(void* const* d_in, const int* in_sizes, int n_in,
                              void* d_out, int out_size, void* d_ws, size_t ws_size,
                              hipStream_t stream) {
    const float* labels = (const float*)d_in[0];   // (2,4,80,80,80) f32
    const float* img    = (const float*)d_in[1];   // (2,1,80,80,80) f32
    float* out = (float*)d_out;                    // 1 float
    (void)d_ws; (void)ws_size;                     // module-scope scratch

    hipLaunchKernelGGL(convdw_sums_kernel, dim3(NBLK1), dim3(256), 0, stream, labels, img);
    hipLaunchKernelGGL(convh_dot_kernel,   dim3(NBLK2), dim3(256), 0, stream, labels, img);
    hipLaunchKernelGGL(final_kernel,       dim3(1),     dim3(256), 0, stream, out);
}